// Round 7
// baseline (120.544 us; speedup 1.0000x reference)
//
#include <hip/hip_runtime.h>
#include <hip/hip_bf16.h>
#include <math.h>

#define HIDDEN 1024
#define EMB    256
#define BROWS  4096
#define CAND   128
#define LN_EPS 1e-12f

#define NC     8          // candidates per wave-iteration
#define NWTOT  2048       // total waves (512 blocks x 4 waves)
#define NITER  32         // (4096*128/NC) / NWTOT

typedef __attribute__((ext_vector_type(8))) short bf16x8;
typedef __attribute__((ext_vector_type(4))) float f32x4;

__device__ __forceinline__ int swz(int row, int slot) { return slot ^ ((row >> 1) & 3); }

__device__ __forceinline__ unsigned short f2bf(float f) {
    __bf16 h = (__bf16)f;
    return __builtin_bit_cast(unsigned short, h);
}

__device__ __forceinline__ float gelu(float x) {
    return 0.5f * x * (1.0f + erff(x * 0.70710678118654752f));
}

// ---------------------------------------------------------------------------
// Split-K GEMM (unchanged from round 6): P[s] = A[:,sK] @ W[:,sK]^T
// ---------------------------------------------------------------------------
__global__ __launch_bounds__(256) void k_gemm_partial(
    const float* __restrict__ A,
    const float* __restrict__ W,
    float* __restrict__ P)               // [4][4096][256]
{
    __shared__ unsigned short As[16 * 32];
    __shared__ unsigned short Ws[256 * 32];

    const int tid  = threadIdx.x;
    const int lane = tid & 63;
    const int wv   = tid >> 6;
    const int m0   = blockIdx.x * 16;
    const int ks   = blockIdx.y;
    const int kbeg = ks * 256;

    const int lcol = lane & 15;
    const int lk   = lane >> 4;
    const int arow = tid >> 2, apr = tid & 3;

    float4 a0, a1, w0[4], w1[4];

#define LOADREGS(KT)                                                          \
    if (tid < 64) {                                                           \
        a0 = *(const float4*)&A[(size_t)(m0 + arow) * HIDDEN + (KT) + apr * 8];     \
        a1 = *(const float4*)&A[(size_t)(m0 + arow) * HIDDEN + (KT) + apr * 8 + 4]; \
    }                                                                         \
    _Pragma("unroll")                                                         \
    for (int i = 0; i < 4; ++i) {                                             \
        int id = tid + i * 256;                                               \
        int row = id >> 2, pr = id & 3;                                       \
        w0[i] = *(const float4*)&W[(size_t)row * HIDDEN + (KT) + pr * 8];     \
        w1[i] = *(const float4*)&W[(size_t)row * HIDDEN + (KT) + pr * 8 + 4]; \
    }

    f32x4 acc[4] = {};
    LOADREGS(kbeg)

    for (int it = 0; it < 8; ++it) {
        __syncthreads();
        if (tid < 64) {
            bf16x8 v;
            v[0]=f2bf(a0.x); v[1]=f2bf(a0.y); v[2]=f2bf(a0.z); v[3]=f2bf(a0.w);
            v[4]=f2bf(a1.x); v[5]=f2bf(a1.y); v[6]=f2bf(a1.z); v[7]=f2bf(a1.w);
            *(bf16x8*)&As[arow * 32 + swz(arow, apr) * 8] = v;
        }
        #pragma unroll
        for (int i = 0; i < 4; ++i) {
            int id = tid + i * 256;
            int row = id >> 2, pr = id & 3;
            bf16x8 v;
            v[0]=f2bf(w0[i].x); v[1]=f2bf(w0[i].y); v[2]=f2bf(w0[i].z); v[3]=f2bf(w0[i].w);
            v[4]=f2bf(w1[i].x); v[5]=f2bf(w1[i].y); v[6]=f2bf(w1[i].z); v[7]=f2bf(w1[i].w);
            *(bf16x8*)&Ws[row * 32 + swz(row, pr) * 8] = v;
        }
        __syncthreads();
        if (it < 7) { LOADREGS(kbeg + (it + 1) * 32) }
        bf16x8 af = *(const bf16x8*)&As[lcol * 32 + swz(lcol, lk) * 8];
        bf16x8 bfr[4];
        #pragma unroll
        for (int n = 0; n < 4; ++n) {
            int r = wv * 64 + n * 16 + lcol;
            bfr[n] = *(const bf16x8*)&Ws[r * 32 + swz(r, lk) * 8];
        }
        #pragma unroll
        for (int n = 0; n < 4; ++n)
            acc[n] = __builtin_amdgcn_mfma_f32_16x16x32_bf16(af, bfr[n], acc[n], 0, 0, 0);
    }
#undef LOADREGS

    float* Pout = P + (size_t)ks * ((size_t)BROWS * EMB);
    #pragma unroll
    for (int n = 0; n < 4; ++n)
        #pragma unroll
        for (int r = 0; r < 4; ++r) {
            int R   = lk * 4 + r;
            int col = wv * 64 + n * 16 + lcol;
            Pout[(size_t)(m0 + R) * EMB + col] = acc[n][r];
        }
}

// ---------------------------------------------------------------------------
// Finalize (unchanged from round 6)
// ---------------------------------------------------------------------------
__global__ __launch_bounds__(256) void k_finalize(
    const float* __restrict__ P,
    const float* __restrict__ bias,
    const float* __restrict__ gamma,
    const float* __restrict__ beta,
    float* __restrict__ G)
{
    const int tid  = threadIdx.x;
    const int lane = tid & 63;
    const int row  = blockIdx.x * 4 + (tid >> 6);
    const size_t off = (size_t)row * EMB + lane * 4;
    const size_t S   = (size_t)BROWS * EMB;

    float4 v0 = *(const float4*)&P[off];
    float4 v1 = *(const float4*)&P[off + S];
    float4 v2 = *(const float4*)&P[off + 2 * S];
    float4 v3 = *(const float4*)&P[off + 3 * S];
    float4 bb = *(const float4*)&bias[lane * 4];

    float4 h;
    h.x = gelu(v0.x + v1.x + v2.x + v3.x + bb.x);
    h.y = gelu(v0.y + v1.y + v2.y + v3.y + bb.y);
    h.z = gelu(v0.z + v1.z + v2.z + v3.z + bb.z);
    h.w = gelu(v0.w + v1.w + v2.w + v3.w + bb.w);

    float s = h.x + h.y + h.z + h.w;
    #pragma unroll
    for (int m = 32; m >= 1; m >>= 1) s += __shfl_xor(s, m);
    const float mu = s * (1.0f / 256.0f);

    const float dx = h.x - mu, dy = h.y - mu, dz = h.z - mu, dw = h.w - mu;
    float q = dx * dx + dy * dy + dz * dz + dw * dw;
    #pragma unroll
    for (int m = 32; m >= 1; m >>= 1) q += __shfl_xor(q, m);
    const float rs = rsqrtf(q * (1.0f / 256.0f) + LN_EPS);

    float4 g  = *(const float4*)&gamma[lane * 4];
    float4 be = *(const float4*)&beta[lane * 4];
    float4 o;
    o.x = dx * rs * g.x + be.x;
    o.y = dy * rs * g.y + be.y;
    o.z = dz * rs * g.z + be.z;
    o.w = dw * rs * g.w + be.w;
    *(float4*)&G[off] = o;
}

// ---------------------------------------------------------------------------
// scores: persistent double-buffered LDS-DMA gather.
// 512 blocks x 4 waves; wave = 32 chunks of 8 candidates; two private 8KB
// LDS buffers. Per iter: prefetch idx(i+2)/H(i+1)/eb(i+1), issue DMA(i+1),
// consume buf(i) behind counted vmcnt(12)/vmcnt(8) (counts include only
// provably-ordered ops: rest of DMA(i) + all DMA(i+1) -> compiler load
// scheduling can only over-wait, never under-wait). DMA stream never drains.
// ---------------------------------------------------------------------------
__global__ __launch_bounds__(256) void k_scores(
    const float* __restrict__ Hf,
    const float* __restrict__ table,
    const float* __restrict__ ebias,
    const int*   __restrict__ cidx,
    float* __restrict__ out)
{
    __shared__ float smem[16384];            // 64 KB: 4 waves x 2 bufs x 8 rows x 1KB
    const int tid  = threadIdx.x;
    const int lane = tid & 63;
    const int wv   = tid >> 6;
    const int l    = lane & 15;
    const int q    = lane >> 4;              // candidate-within-group 0..3
    const int w    = blockIdx.x * 4 + wv;    // global wave id 0..2047

    float* buf0 = &smem[wv * 4096];
    float* buf1 = buf0 + 2048;

#define CH(IT) ((((IT) < NITER) ? (IT) : (NITER - 1)) * NWTOT + w)

    // ---- prologue ----
    int ia = cidx[(size_t)CH(0) * NC + (l & 7)];   // idx for chunk 0 (lane r<8 holds cand r)
    int ib = cidx[(size_t)CH(1) * NC + (l & 7)];   // idx for chunk 1
    float4 ha[4];
    {
        const float4* Hr = (const float4*)(Hf + (size_t)(CH(0) >> 4) * EMB);
        #pragma unroll
        for (int p = 0; p < 4; ++p) ha[p] = Hr[p * 16 + l];
    }
    float ea = ebias[ia];
    #pragma unroll
    for (int r = 0; r < NC; ++r) {                 // DMA(0) -> buf0
        int ix = __shfl(ia, r);
        const float* gs = table + (size_t)ix * EMB + lane * 4;
        __builtin_amdgcn_global_load_lds(
            (const __attribute__((address_space(1))) void*)gs,
            (__attribute__((address_space(3))) void*)(buf0 + r * 256),
            16, 0, 0);
    }

    // ---- main loop ----
    #pragma unroll 2
    for (int it = 0; it < NITER; ++it) {
        float* bcur = (it & 1) ? buf1 : buf0;
        float* bnxt = (it & 1) ? buf0 : buf1;

        // A: idx prefetch for it+2
        int ic = cidx[(size_t)CH(it + 2) * NC + (l & 7)];
        // B: H prefetch for it+1
        float4 hn[4];
        {
            const float4* Hr = (const float4*)(Hf + (size_t)(CH(it + 1) >> 4) * EMB);
            #pragma unroll
            for (int p = 0; p < 4; ++p) hn[p] = Hr[p * 16 + l];
        }
        // F: ebias prefetch for it+1 (before DMA issue so no wait can strand it)
        float en = ebias[ib];
        // C: issue DMA(it+1) into bnxt
        #pragma unroll
        for (int r = 0; r < NC; ++r) {
            int ix = __shfl(ib, r);
            const float* gs = table + (size_t)ix * EMB + lane * 4;
            __builtin_amdgcn_global_load_lds(
                (const __attribute__((address_space(1))) void*)gs,
                (__attribute__((address_space(3))) void*)(bnxt + r * 256),
                16, 0, 0);
        }

        // D: consume buf(it): group 0 = cand q, group 1 = cand 4+q
        float res0, res1;
        asm volatile("s_waitcnt vmcnt(12)" ::: "memory");
        {
            const float4* row = (const float4*)(bcur + q * 256);
            float s = 0.f;
            #pragma unroll
            for (int p = 0; p < 4; ++p) {
                float4 t = row[p * 16 + l];
                s += t.x * ha[p].x + t.y * ha[p].y + t.z * ha[p].z + t.w * ha[p].w;
            }
            #pragma unroll
            for (int m = 8; m >= 1; m >>= 1) s += __shfl_xor(s, m);
            res0 = s;
        }
        asm volatile("s_waitcnt vmcnt(8)" ::: "memory");
        {
            const float4* row = (const float4*)(bcur + (4 + q) * 256);
            float s = 0.f;
            #pragma unroll
            for (int p = 0; p < 4; ++p) {
                float4 t = row[p * 16 + l];
                s += t.x * ha[p].x + t.y * ha[p].y + t.z * ha[p].z + t.w * ha[p].w;
            }
            #pragma unroll
            for (int m = 8; m >= 1; m >>= 1) s += __shfl_xor(s, m);
            res1 = s;
        }

        // E: write results for chunk it
        {
            const size_t obase = (size_t)CH(it) * NC;
            float e0 = __shfl(ea, q);
            float e1 = __shfl(ea, 4 + q);
            if (l == 0) {
                out[obase + q]     = res0 + e0;
                out[obase + 4 + q] = res1 + e1;
            }
        }

        // rotate pipeline registers
        ia = ib; ib = ic;
        ea = en;
        #pragma unroll
        for (int p = 0; p < 4; ++p) ha[p] = hn[p];
    }
#undef CH
}

// ---------------------------------------------------------------------------
extern "C" void kernel_launch(void* const* d_in, const int* in_sizes, int n_in,
                              void* d_out, int out_size, void* d_ws, size_t ws_size,
                              hipStream_t stream) {
    const float* hidden = (const float*)d_in[0];
    const float* Wd     = (const float*)d_in[1];
    const float* bd     = (const float*)d_in[2];
    const float* gamma  = (const float*)d_in[3];
    const float* beta   = (const float*)d_in[4];
    const float* table  = (const float*)d_in[5];
    const float* ebias  = (const float*)d_in[6];
    const int*   cidx   = (const int*)d_in[7];
    float* out = (float*)d_out;

    char* ws = (char*)d_ws;
    float* G = (float*)ws;                          // 4 MB
    float* P = (float*)(ws + 4 * 1024 * 1024);      // 16 MB (4 x [4096,256] f32)

    k_gemm_partial<<<dim3(BROWS / 16, 4), 256, 0, stream>>>(hidden, Wd, P);
    k_finalize<<<dim3(BROWS / 4), 256, 0, stream>>>(P, bd, gamma, beta, G);
    k_scores<<<dim3(512), 256, 0, stream>>>(G, table, ebias, cidx, out);
}